// Round 6
// baseline (10368.555 us; speedup 1.0000x reference)
//
#include <hip/hip_runtime.h>
#include <hip/hip_bf16.h>
#include <math.h>

#define BATCH 4
#define SEQ   2048
#define DIM   1024
#define MROWS (SEQ*BATCH)          // 8192
#define BIGN  ((size_t)MROWS*DIM)  // 8388608 floats per buffer

typedef float v2f __attribute__((ext_vector_type(2)));

// ---------------- chunked scan for r_t = dec*r + k*v,  ret = q*r --------------
__global__ __launch_bounds__(256) void scan_a(const float* __restrict__ K,
    const float* __restrict__ V, const float* __restrict__ dec_p,
    float* __restrict__ E)
{
  int id  = blockIdx.x*256 + threadIdx.x;   // 0..262143
  int c   = id >> 12;
  int rem = id & 4095;
  int b   = rem >> 10;
  int dc  = rem & 1023;
  float dec = dec_p[dc >> 6];
  size_t base = ((size_t)b*SEQ + (size_t)c*32)*DIM + dc;
  float r = 0.f;
  #pragma unroll 4
  for (int i = 0; i < 32; ++i) {
    float kv = K[base + (size_t)i*DIM] * V[base + (size_t)i*DIM];
    r = fmaf(dec, r, kv);
  }
  E[(size_t)c*4096 + rem] = r;
}

__global__ __launch_bounds__(256) void scan_b(const float* __restrict__ E,
    const float* __restrict__ dec_p, float* __restrict__ carry)
{
  int id = blockIdx.x*256 + threadIdx.x;    // 0..4095
  int dc = id & 1023;
  float dec = dec_p[dc >> 6];
  float d2 = dec*dec, d4 = d2*d2, d8 = d4*d4, d16 = d8*d8, d32 = d16*d16;
  float r = 0.f;
  #pragma unroll 1
  for (int c = 0; c < 64; ++c) {
    carry[(size_t)c*4096 + id] = r;
    r = fmaf(d32, r, E[(size_t)c*4096 + id]);
  }
}

__global__ __launch_bounds__(256) void scan_c(const float* __restrict__ Q,
    const float* __restrict__ K, const float* __restrict__ V,
    const float* __restrict__ dec_p, const float* __restrict__ carry,
    float* __restrict__ ret)
{
  int id  = blockIdx.x*256 + threadIdx.x;
  int c   = id >> 12;
  int rem = id & 4095;
  int b   = rem >> 10;
  int dc  = rem & 1023;
  float dec = dec_p[dc >> 6];
  size_t base = ((size_t)b*SEQ + (size_t)c*32)*DIM + dc;
  float r = carry[(size_t)c*4096 + rem];
  #pragma unroll 1
  for (int i = 0; i < 32; ++i) {
    int t = c*32 + i;
    float kv = K[base + (size_t)i*DIM] * V[base + (size_t)i*DIM];
    r = fmaf(dec, r, kv);
    ret[((size_t)t*BATCH + b)*DIM + dc] = Q[base + (size_t)i*DIM] * r;
  }
}

// ---------------- fp32 tiled GEMM: C[m,n] = sum_k X[m,k]*W[n,k] (+bias) -------
// MODE 0: C = XW^T + bias
// MODE 1: g = sigmoid(XW^T + bias) -> C;  u_out = (1-g)*inp
// MODE 2: C += XW^T
// MODE 3: outf[b,t,n] = XW^T + bias   (m = t*4+b scatter), float32 output
// MODE 4: C = XW^T
// 128x128 tile, 8x8 per thread, packed v_pk_fma_f32.
#define GM 128
#define GN 128
#define GK 16
#define LDG 132

template<int MODE>
__global__ __launch_bounds__(256) void gemm_k(
    const float* __restrict__ X, const float* __restrict__ W,
    const float* __restrict__ bias, float* __restrict__ C,
    const float* __restrict__ inp, float* __restrict__ u_out,
    float* __restrict__ outf)
{
  __shared__ float Xs[GK][LDG];
  __shared__ float Ws[GK][LDG];
  const int tid = threadIdx.x;
  const int m0 = blockIdx.y * GM;
  const int n0 = blockIdx.x * GN;
  const int tx = tid & 15, ty = tid >> 4;
  v2f acc[8][4] = {};
  #pragma unroll 1
  for (int kb = 0; kb < DIM; kb += GK) {
    #pragma unroll
    for (int h = 0; h < 2; ++h) {
      int idx = tid + h*256;
      int r   = idx >> 2;         // 0..127
      int kc  = (idx & 3) << 2;   // 0,4,8,12
      float4 xv = *(const float4*)(X + (size_t)(m0+r)*DIM + kb + kc);
      Xs[kc+0][r] = xv.x; Xs[kc+1][r] = xv.y;
      Xs[kc+2][r] = xv.z; Xs[kc+3][r] = xv.w;
      float4 wv2 = *(const float4*)(W + (size_t)(n0+r)*DIM + kb + kc);
      Ws[kc+0][r] = wv2.x; Ws[kc+1][r] = wv2.y;
      Ws[kc+2][r] = wv2.z; Ws[kc+3][r] = wv2.w;
    }
    __syncthreads();
    #pragma unroll
    for (int kk = 0; kk < GK; ++kk) {
      float4 a0 = *(const float4*)&Xs[kk][ty*8];
      float4 a1 = *(const float4*)&Xs[kk][ty*8 + 4];
      float4 w0 = *(const float4*)&Ws[kk][tx*4];        // cols tx*4..+3
      float4 w1 = *(const float4*)&Ws[kk][64 + tx*4];   // cols 64+tx*4..+3
      v2f wv[4] = {{w0.x,w0.y},{w0.z,w0.w},{w1.x,w1.y},{w1.z,w1.w}};
      float av[8] = {a0.x,a0.y,a0.z,a0.w,a1.x,a1.y,a1.z,a1.w};
      #pragma unroll
      for (int i = 0; i < 8; ++i) {
        v2f ab = {av[i], av[i]};
        #pragma unroll
        for (int j = 0; j < 4; ++j)
          acc[i][j] = __builtin_elementwise_fma(ab, wv[j], acc[i][j]);
      }
    }
    __syncthreads();
  }
  float bj[8];
  #pragma unroll
  for (int j = 0; j < 8; ++j) {
    int n = n0 + ((j < 4) ? (tx*4 + j) : (64 + tx*4 + (j - 4)));
    bj[j] = (MODE == 0 || MODE == 1 || MODE == 3) ? bias[n] : 0.f;
  }
  #pragma unroll
  for (int i = 0; i < 8; ++i) {
    int m = m0 + ty*8 + i;
    #pragma unroll
    for (int j = 0; j < 8; ++j) {
      int n = n0 + ((j < 4) ? (tx*4 + j) : (64 + tx*4 + (j - 4)));
      size_t off = (size_t)m*DIM + n;
      float vv = acc[i][j >> 1][j & 1] + bj[j];
      if (MODE == 2) vv += C[off];
      if (MODE == 1) {
        float gv = 1.f/(1.f + expf(-vv));
        C[off] = gv;
        u_out[off] = (1.f - gv) * inp[off];
      } else if (MODE == 3) {
        outf[((size_t)(m & 3)*SEQ + (size_t)(m >> 2))*DIM + n] = vv;
      } else {
        C[off] = vv;
      }
    }
  }
}

// ---------------- sequential recurrence: s_t = tanh((g_t*s_{t-1})@A^T + d_t) --
// r6 design — INTERLEAVED BATCHES: r2 vs r5 proved step time is sync-chain
// latency (~4300cyc), not compute (8x DS-traffic change moved nothing). So
// hide the hop latency under the 3 OTHER independent batch chains:
//
// Grid 32 x 512. Block blk owns rows [blk*32, +32) for ALL 4 batches (A-frag
// in regs, reused 4x). Per macro-step t: process batches 0..3 in order.
// During batch j:
//   - pre-issue the poll SAMPLE for the next batch-step (its data was
//     published >=3 batch-computes ago -> sample returns fresh; its vmcnt
//     wait retires under compute -> ~zero sync on the critical path)
//   - prefetch g/dpre TWO batches ahead (covers HBM latency)
//   - all issues happen BEFORE this batch's publish store, so value-waits
//     never drain the store's IC ack (the r3 trap, latent in r2/r5 too:
//     their prefetch was after the publish).
// One lgkm-only stage barrier per batch; NO end barriers (barrier spacing
// bounds wave drift; xs regions are per-batch).
//
// Ring: sf[2][4][512] packed words {f32 x2i, f32 x2i+1}, step tag in each
// float's mantissa LSB (tag(t)=((t+2)>>1)&1; 2^-24 perturbation, proven
// r3-r5). Thread tid polls word tid of the batch. Reuse-safety proof as
// before, per batch: publishing tag(T-1) implies having consumed slot
// (T-2)&1, so overwriting slot T&1 at T is safe.
//
// Per-wave split: wave w owns rows r0=blk*32+w*4 .. +3; lane l owns cols
// {256q+4l..+3, q=0..3} (16/row). matvec = 32 pk-fma; row totals via
// 2 fold stages (masks 2,1 -> lane l holds row l&3) + 4 plain butterflies.
#define RBLK 32

__global__ __launch_bounds__(512, 2) void recur_k(
    const float* __restrict__ A, const float* __restrict__ g,
    const float* __restrict__ dpre, float* __restrict__ s,
    unsigned long long* __restrict__ sf)
{
  __shared__ __align__(16) float xs[4][1024];   // 16 KB, one region per batch
  const int tid = threadIdx.x;
  const int w   = tid >> 6;                 // wave 0..7
  const int ln  = tid & 63;
  const int blk = blockIdx.x;               // 0..31
  const int r0  = blk*32 + w*4;             // first of this wave's 4 rows
  const int myrow = r0 + (ln & 3);          // row this lane evaluates

  // A fragment: 4 rows x {256q + 4*ln .. +3}
  v2f af[4][4][2];
  #pragma unroll
  for (int r = 0; r < 4; ++r)
    #pragma unroll
    for (int q = 0; q < 4; ++q) {
      float4 t4 = *(const float4*)(A + (size_t)(r0 + r)*DIM + q*256 + 4*ln);
      af[r][q][0] = (v2f){t4.x, t4.y};
      af[r][q][1] = (v2f){t4.z, t4.w};
    }

  float2 gv[4]; float dv[4];
  unsigned long long samp[4] = {0ull, 0ull, 0ull, 0ull};
  // seed prefetches for (t=0, b=0) and (t=0, b=1); rest roll forward
  gv[0] = *(const float2*)(g + (size_t)0*DIM + 2*tid);
  dv[0] = dpre[(size_t)0*DIM + myrow];
  gv[1] = *(const float2*)(g + (size_t)1*DIM + 2*tid);
  dv[1] = dpre[(size_t)1*DIM + myrow];

  #pragma unroll 1
  for (int t = 0; t < SEQ; ++t) {
    #pragma unroll
    for (int j = 0; j < 4; ++j) {
      const int i1 = (j + 1) & 3;
      const int i2 = (j + 2) & 3;
      float sr0 = 0.f, sr1 = 0.f, sr2 = 0.f, sr3 = 0.f;

      if (t > 0) {
        // consume batch j's x-word (floats 2tid, 2tid+1)
        const unsigned wl = ((unsigned)(t + 1) >> 1) & 1u;   // tag(t-1)
        unsigned long long* pw =
            sf + (size_t)((t - 1) & 1)*2048 + j*512 + tid;
        union { unsigned long long u; float f[2]; } wv;
        if ((unsigned)(samp[j] & 1u) == wl) {
          wv.u = samp[j];               // pre-issued sample was fresh
        } else {
          int guard = 0;
          for (;;) {
            unsigned long long x0 = __hip_atomic_load(pw, __ATOMIC_RELAXED,
                                     __HIP_MEMORY_SCOPE_AGENT);
            unsigned long long x1 = __hip_atomic_load(pw, __ATOMIC_RELAXED,
                                     __HIP_MEMORY_SCOPE_AGENT);
            if ((unsigned)(x0 & 1u) == wl) { wv.u = x0; break; }
            if ((unsigned)(x1 & 1u) == wl) { wv.u = x1; break; }
            if (++guard > (1 << 22))       { wv.u = x1; break; }
          }
        }
        // stage x = g * s[t-1] into this batch's region
        *(float2*)(&xs[j][2*tid]) =
            make_float2(gv[j].x * wv.f[0], gv[j].y * wv.f[1]);
        asm volatile("s_waitcnt lgkmcnt(0)\n\ts_barrier" ::: "memory");
      }

      // pipelined issues — all BEFORE this batch's publish store
      {
        int Tg = (j < 2) ? t : t + 1;          // g/d two batch-steps ahead
        if (Tg < SEQ) {
          gv[i2] = *(const float2*)(g + ((size_t)Tg*4 + i2)*DIM + 2*tid);
          dv[i2] = dpre[((size_t)Tg*4 + i2)*DIM + myrow];
        }
        int Tc = (j < 3) ? t : t + 1;          // sample one batch-step ahead
        if (Tc == 0) Tc = 1;
        if (Tc < SEQ)
          samp[i1] = __hip_atomic_load(
              sf + (size_t)((Tc - 1) & 1)*2048 + i1*512 + tid,
              __ATOMIC_RELAXED, __HIP_MEMORY_SCOPE_AGENT);
        asm volatile("" ::: "memory");   // pin issue points
      }

      if (t > 0) {
        // x slice once (4x b128, conflict-free), reuse across 4 rows
        const float* xb = xs[j];
        v2f xq[4][2];
        #pragma unroll
        for (int q = 0; q < 4; ++q) {
          float4 xt = *(const float4*)(xb + q*256 + 4*ln);
          xq[q][0] = (v2f){xt.x, xt.y};
          xq[q][1] = (v2f){xt.z, xt.w};
        }
        v2f c0 = {0.f,0.f}, c1 = {0.f,0.f}, c2 = {0.f,0.f}, c3 = {0.f,0.f};
        #pragma unroll
        for (int q = 0; q < 4; ++q) {
          c0 = __builtin_elementwise_fma(af[0][q][0], xq[q][0], c0);
          c0 = __builtin_elementwise_fma(af[0][q][1], xq[q][1], c0);
          c1 = __builtin_elementwise_fma(af[1][q][0], xq[q][0], c1);
          c1 = __builtin_elementwise_fma(af[1][q][1], xq[q][1], c1);
          c2 = __builtin_elementwise_fma(af[2][q][0], xq[q][0], c2);
          c2 = __builtin_elementwise_fma(af[2][q][1], xq[q][1], c2);
          c3 = __builtin_elementwise_fma(af[3][q][0], xq[q][0], c3);
          c3 = __builtin_elementwise_fma(af[3][q][1], xq[q][1], c3);
        }
        sr0 = c0.x + c0.y; sr1 = c1.x + c1.y;
        sr2 = c2.x + c2.y; sr3 = c3.x + c3.y;
      }

      // fold: masks 2,1 (lane l ends with row l&3), then 4,8,16,32
      float u0, u1, v1;
      { float lo = sr0 + __shfl_xor(sr0, 2, 64);
        float hi = sr2 + __shfl_xor(sr2, 2, 64);
        u0 = (ln & 2) ? hi : lo; }
      { float lo = sr1 + __shfl_xor(sr1, 2, 64);
        float hi = sr3 + __shfl_xor(sr3, 2, 64);
        u1 = (ln & 2) ? hi : lo; }
      { float lo = u0 + __shfl_xor(u0, 1, 64);
        float hi = u1 + __shfl_xor(u1, 1, 64);
        v1 = (ln & 1) ? hi : lo; }
      v1 += __shfl_xor(v1, 4, 64);
      v1 += __shfl_xor(v1, 8, 64);
      v1 += __shfl_xor(v1, 16, 64);
      v1 += __shfl_xor(v1, 32, 64);

      // fast tanh: 1 - 2/(e^{2x}+1); exp2 saturates correctly at +-inf
      float zz  = v1 + dv[j];
      float e2x = __builtin_amdgcn_exp2f(zz * 2.8853900817779268f);
      float val = 1.0f - 2.0f * __builtin_amdgcn_rcpf(e2x + 1.0f);
      float pv  = __shfl_xor(val, 1, 64);    // lane 2m gets row 2m+1's value
      const unsigned tg = ((unsigned)(t + 2) >> 1) & 1u;
      if ((ln & 61) == 0) {                  // ln==0 (rows r0,r0+1) or ln==2
        union { unsigned long long u; unsigned ui[2]; } pk;
        pk.ui[0] = (__float_as_uint(val) & ~1u) | tg;
        pk.ui[1] = (__float_as_uint(pv)  & ~1u) | tg;
        __hip_atomic_store(
            sf + (size_t)(t & 1)*2048 + j*512 + (blk*16 + w*2 + (ln >> 1)),
            pk.u, __ATOMIC_RELAXED, __HIP_MEMORY_SCOPE_AGENT);
        // plain store for the output GEMM (kernel-boundary visibility)
        *(float2*)(s + ((size_t)t*4 + j)*DIM + r0 + ln) = make_float2(val, pv);
      }
      // no end barrier: next batch's stage barrier bounds wave drift
    }
  }
}

// ------------------------------------------------------------------------------
extern "C" void kernel_launch(void* const* d_in, const int* in_sizes, int n_in,
                              void* d_out, int out_size, void* d_ws, size_t ws_size,
                              hipStream_t stream)
{
  (void)in_sizes; (void)n_in; (void)out_size;
  const float* q   = (const float*)d_in[0];
  const float* k   = (const float*)d_in[1];
  const float* v   = (const float*)d_in[2];
  const float* Wi  = (const float*)d_in[3];
  const float* bi  = (const float*)d_in[4];
  const float* Wg  = (const float*)d_in[5];
  const float* bg  = (const float*)d_in[6];
  const float* A   = (const float*)d_in[7];
  const float* Bm  = (const float*)d_in[8];
  const float* Wo  = (const float*)d_in[9];
  const float* bo  = (const float*)d_in[10];
  const float* dec = (const float*)d_in[11];

  const size_t sf_bytes = (size_t)2*4*512*sizeof(unsigned long long); // 32KB
  size_t need = (4*BIGN + 2*(size_t)64*4096)*sizeof(float) + sf_bytes;
  if (ws_size < need) return;

  float* b0 = (float*)d_ws;          // ret -> u -> s
  float* b1 = b0 + BIGN;             // inp
  float* b2 = b1 + BIGN;             // g
  float* b3 = b2 + BIGN;             // d  (pre-activation constant)
  float* E     = b3 + BIGN;
  float* carry = E + (size_t)64*4096;
  unsigned long long* sf = (unsigned long long*)(carry + (size_t)64*4096);
  float* outp  = (float*)d_out;

  hipMemsetAsync(sf, 0, sf_bytes, stream);

  scan_a<<<1024, 256, 0, stream>>>(k, v, dec, E);
  scan_b<<<16,   256, 0, stream>>>(E, dec, carry);
  scan_c<<<1024, 256, 0, stream>>>(q, k, v, dec, carry, b0);

  dim3 gg(DIM/GN, MROWS/GM);   // (8, 64)
  gemm_k<0><<<gg, 256, 0, stream>>>(b0, Wi, bi, b1, nullptr, nullptr, nullptr); // inp
  gemm_k<1><<<gg, 256, 0, stream>>>(b1, Wg, bg, b2, b1, b0, nullptr);           // g, u
  gemm_k<4><<<gg, 256, 0, stream>>>(b0, A,  nullptr, b3, nullptr, nullptr, nullptr); // d  = u@A^T
  gemm_k<2><<<gg, 256, 0, stream>>>(b1, Bm, nullptr, b3, nullptr, nullptr, nullptr); // d += inp@Bm^T

  recur_k<<<RBLK, 512, 0, stream>>>(A, b2, b3, b0, sf);                         // s

  gemm_k<3><<<gg, 256, 0, stream>>>(b0, Wo, bo, nullptr, nullptr, nullptr, outp); // out
}

// Round 7
// 6622.717 us; speedup vs baseline: 1.5656x; 1.5656x over previous
//
#include <hip/hip_runtime.h>
#include <hip/hip_bf16.h>
#include <math.h>

#define BATCH 4
#define SEQ   2048
#define DIM   1024
#define MROWS (SEQ*BATCH)          // 8192
#define BIGN  ((size_t)MROWS*DIM)  // 8388608 floats per buffer

typedef float v2f __attribute__((ext_vector_type(2)));

// ---------------- chunked scan for r_t = dec*r + k*v,  ret = q*r --------------
__global__ __launch_bounds__(256) void scan_a(const float* __restrict__ K,
    const float* __restrict__ V, const float* __restrict__ dec_p,
    float* __restrict__ E)
{
  int id  = blockIdx.x*256 + threadIdx.x;   // 0..262143
  int c   = id >> 12;
  int rem = id & 4095;
  int b   = rem >> 10;
  int dc  = rem & 1023;
  float dec = dec_p[dc >> 6];
  size_t base = ((size_t)b*SEQ + (size_t)c*32)*DIM + dc;
  float r = 0.f;
  #pragma unroll 4
  for (int i = 0; i < 32; ++i) {
    float kv = K[base + (size_t)i*DIM] * V[base + (size_t)i*DIM];
    r = fmaf(dec, r, kv);
  }
  E[(size_t)c*4096 + rem] = r;
}

__global__ __launch_bounds__(256) void scan_b(const float* __restrict__ E,
    const float* __restrict__ dec_p, float* __restrict__ carry)
{
  int id = blockIdx.x*256 + threadIdx.x;    // 0..4095
  int dc = id & 1023;
  float dec = dec_p[dc >> 6];
  float d2 = dec*dec, d4 = d2*d2, d8 = d4*d4, d16 = d8*d8, d32 = d16*d16;
  float r = 0.f;
  #pragma unroll 1
  for (int c = 0; c < 64; ++c) {
    carry[(size_t)c*4096 + id] = r;
    r = fmaf(d32, r, E[(size_t)c*4096 + id]);
  }
}

__global__ __launch_bounds__(256) void scan_c(const float* __restrict__ Q,
    const float* __restrict__ K, const float* __restrict__ V,
    const float* __restrict__ dec_p, const float* __restrict__ carry,
    float* __restrict__ ret)
{
  int id  = blockIdx.x*256 + threadIdx.x;
  int c   = id >> 12;
  int rem = id & 4095;
  int b   = rem >> 10;
  int dc  = rem & 1023;
  float dec = dec_p[dc >> 6];
  size_t base = ((size_t)b*SEQ + (size_t)c*32)*DIM + dc;
  float r = carry[(size_t)c*4096 + rem];
  #pragma unroll 1
  for (int i = 0; i < 32; ++i) {
    int t = c*32 + i;
    float kv = K[base + (size_t)i*DIM] * V[base + (size_t)i*DIM];
    r = fmaf(dec, r, kv);
    ret[((size_t)t*BATCH + b)*DIM + dc] = Q[base + (size_t)i*DIM] * r;
  }
}

// ---------------- fp32 tiled GEMM: C[m,n] = sum_k X[m,k]*W[n,k] (+bias) -------
// MODE 0: C = XW^T + bias
// MODE 1: g = sigmoid(XW^T + bias) -> C;  u_out = (1-g)*inp
// MODE 2: C += XW^T
// MODE 3: outf[b,t,n] = XW^T + bias   (m = t*4+b scatter), float32 output
// MODE 4: C = XW^T
// 128x128 tile, 8x8 per thread, packed v_pk_fma_f32.
#define GM 128
#define GN 128
#define GK 16
#define LDG 132

template<int MODE>
__global__ __launch_bounds__(256) void gemm_k(
    const float* __restrict__ X, const float* __restrict__ W,
    const float* __restrict__ bias, float* __restrict__ C,
    const float* __restrict__ inp, float* __restrict__ u_out,
    float* __restrict__ outf)
{
  __shared__ float Xs[GK][LDG];
  __shared__ float Ws[GK][LDG];
  const int tid = threadIdx.x;
  const int m0 = blockIdx.y * GM;
  const int n0 = blockIdx.x * GN;
  const int tx = tid & 15, ty = tid >> 4;
  v2f acc[8][4] = {};
  #pragma unroll 1
  for (int kb = 0; kb < DIM; kb += GK) {
    #pragma unroll
    for (int h = 0; h < 2; ++h) {
      int idx = tid + h*256;
      int r   = idx >> 2;         // 0..127
      int kc  = (idx & 3) << 2;   // 0,4,8,12
      float4 xv = *(const float4*)(X + (size_t)(m0+r)*DIM + kb + kc);
      Xs[kc+0][r] = xv.x; Xs[kc+1][r] = xv.y;
      Xs[kc+2][r] = xv.z; Xs[kc+3][r] = xv.w;
      float4 wv2 = *(const float4*)(W + (size_t)(n0+r)*DIM + kb + kc);
      Ws[kc+0][r] = wv2.x; Ws[kc+1][r] = wv2.y;
      Ws[kc+2][r] = wv2.z; Ws[kc+3][r] = wv2.w;
    }
    __syncthreads();
    #pragma unroll
    for (int kk = 0; kk < GK; ++kk) {
      float4 a0 = *(const float4*)&Xs[kk][ty*8];
      float4 a1 = *(const float4*)&Xs[kk][ty*8 + 4];
      float4 w0 = *(const float4*)&Ws[kk][tx*4];        // cols tx*4..+3
      float4 w1 = *(const float4*)&Ws[kk][64 + tx*4];   // cols 64+tx*4..+3
      v2f wv[4] = {{w0.x,w0.y},{w0.z,w0.w},{w1.x,w1.y},{w1.z,w1.w}};
      float av[8] = {a0.x,a0.y,a0.z,a0.w,a1.x,a1.y,a1.z,a1.w};
      #pragma unroll
      for (int i = 0; i < 8; ++i) {
        v2f ab = {av[i], av[i]};
        #pragma unroll
        for (int j = 0; j < 4; ++j)
          acc[i][j] = __builtin_elementwise_fma(ab, wv[j], acc[i][j]);
      }
    }
    __syncthreads();
  }
  float bj[8];
  #pragma unroll
  for (int j = 0; j < 8; ++j) {
    int n = n0 + ((j < 4) ? (tx*4 + j) : (64 + tx*4 + (j - 4)));
    bj[j] = (MODE == 0 || MODE == 1 || MODE == 3) ? bias[n] : 0.f;
  }
  #pragma unroll
  for (int i = 0; i < 8; ++i) {
    int m = m0 + ty*8 + i;
    #pragma unroll
    for (int j = 0; j < 8; ++j) {
      int n = n0 + ((j < 4) ? (tx*4 + j) : (64 + tx*4 + (j - 4)));
      size_t off = (size_t)m*DIM + n;
      float vv = acc[i][j >> 1][j & 1] + bj[j];
      if (MODE == 2) vv += C[off];
      if (MODE == 1) {
        float gv = 1.f/(1.f + expf(-vv));
        C[off] = gv;
        u_out[off] = (1.f - gv) * inp[off];
      } else if (MODE == 3) {
        outf[((size_t)(m & 3)*SEQ + (size_t)(m >> 2))*DIM + n] = vv;
      } else {
        C[off] = vv;
      }
    }
  }
}

// ---------------- sequential recurrence: s_t = tanh((g_t*s_{t-1})@A^T + d_t) --
// r7 = r5's proven structure (16 blocks/batch, 64 rows/block, grid 64;
// x amortized over 8 rows in registers; 2-slot LSB-tagged ring) with TWO
// sync-mechanic changes:
//
//  1. ROLLING 4-DEEP POLL QUEUE: r2~r5 showed the step (~4300cyc) is
//     sync-latency dominated; the old poll re-probed only every ~RT
//     (~700-900cyc), so a just-missed probe cost a full RT. Keeping 4
//     samples of the word in flight (check oldest, reissue one per iter)
//     drops the probe period to the loop length (~40-80cyc): discovery
//     ~= visibility + spacing + one-way return instead of +1.5*RT.
//  2. END BARRIER REMOVED: xs is double-buffered and the ring-reuse proof
//     uses only the STAGE barrier (publish of tag(T) happens after T's
//     stage barrier, which certifies all reads of slot (T-2)&1 are done;
//     a block seeing all tag(T) words may safely overwrite slot T&1).
//     t+2's xs write cannot collide with t's reads: t+1's stage barrier
//     is in between. One fewer 8-wave reconvergence per step.
//
// Ring: sf[2][B][512] packed {f32 x2r, f32 x2r+1}, step tag in each
// float's mantissa LSB (tag(t)=((t+2)>>1)&1; 2^-24 perturbation, proven
// r3-r6). Thread tid polls exactly word tid (ONE word).
#define RBLK 64

__global__ __launch_bounds__(512, 2) void recur_k(
    const float* __restrict__ A, const float* __restrict__ g,
    const float* __restrict__ dpre, float* __restrict__ s,
    unsigned long long* __restrict__ sf)
{
  __shared__ __align__(16) float xs[2][1024];   // 8 KB, double-buffered
  const int tid = threadIdx.x;
  const int w   = tid >> 6;                 // wave 0..7
  const int ln  = tid & 63;
  const int b   = blockIdx.x >> 4;          // batch 0..3
  const int blk = blockIdx.x & 15;          // block within batch
  const int r0  = blk*64 + w*8;             // first row of this wave
  const int myrow = r0 + (ln & 7);          // row this lane will hold

  const size_t slotstride = (size_t)BATCH*512;     // ull words per ring slot
  unsigned long long* sfb = sf + (size_t)b*512;    // this batch, slot 0

  // A fragment: 8 rows x {256q + 4*ln .. +3}
  v2f a2[8][4][2];
  #pragma unroll
  for (int r = 0; r < 8; ++r)
    #pragma unroll
    for (int q = 0; q < 4; ++q) {
      float4 t4 = *(const float4*)(A + (size_t)(r0 + r)*DIM + q*256 + ln*4);
      a2[r][q][0] = (v2f){t4.x, t4.y};
      a2[r][q][1] = (v2f){t4.z, t4.w};
    }

  // prologue prefetch (t=0)
  float2 gvc = *(const float2*)(g + (size_t)b*DIM + 2*tid);
  float  dvc = dpre[(size_t)b*DIM + myrow];

  #pragma unroll 1
  for (int t = 0; t < SEQ; ++t) {
    float sr[8] = {};
    if (t > 0) {
      // rolling 4-deep poll of the one flagged word this thread stages
      const unsigned wl = ((unsigned)(t + 1) >> 1) & 1u;   // tag(t-1)
      unsigned long long* pw = sfb + (size_t)((t - 1) & 1)*slotstride + tid;
      union { unsigned long long u; float f[2]; } wv;
      {
        unsigned long long q0 = __hip_atomic_load(pw, __ATOMIC_RELAXED,
                                                  __HIP_MEMORY_SCOPE_AGENT);
        unsigned long long q1 = __hip_atomic_load(pw, __ATOMIC_RELAXED,
                                                  __HIP_MEMORY_SCOPE_AGENT);
        unsigned long long q2 = __hip_atomic_load(pw, __ATOMIC_RELAXED,
                                                  __HIP_MEMORY_SCOPE_AGENT);
        unsigned long long q3 = __hip_atomic_load(pw, __ATOMIC_RELAXED,
                                                  __HIP_MEMORY_SCOPE_AGENT);
        int guard = 0;
        for (;;) {
          if ((unsigned)(q0 & 1u) == wl) { wv.u = q0; break; }
          if (++guard > (1 << 24))       { wv.u = q0; break; }
          q0 = q1; q1 = q2; q2 = q3;
          q3 = __hip_atomic_load(pw, __ATOMIC_RELAXED,
                                 __HIP_MEMORY_SCOPE_AGENT);
        }
      }

      // stage x = g * s[t-1][b] (linear layout, conflict-free float2 write)
      float* xb = xs[t & 1];
      *(float2*)(xb + 2*tid) = make_float2(gvc.x * wv.f[0], gvc.y * wv.f[1]);
      asm volatile("s_waitcnt lgkmcnt(0)\n\ts_barrier" ::: "memory");

      // x slice ONCE into regs (4x b128, conflict-free), reuse for 8 rows
      v2f xq[4][2];
      #pragma unroll
      for (int q = 0; q < 4; ++q) {
        float4 xt = *(const float4*)(xb + q*256 + ln*4);
        xq[q][0] = (v2f){xt.x, xt.y};
        xq[q][1] = (v2f){xt.z, xt.w};
      }
      #pragma unroll
      for (int r = 0; r < 8; ++r) {
        v2f acc = {0.f, 0.f};
        #pragma unroll
        for (int q = 0; q < 4; ++q) {
          acc = __builtin_elementwise_fma(a2[r][q][0], xq[q][0], acc);
          acc = __builtin_elementwise_fma(a2[r][q][1], xq[q][1], acc);
        }
        sr[r] = acc.x + acc.y;
      }
    }
    // fold reduce: masks 4,2,1 (lane l ends with row l&7), then 8,16,32
    float v4[4];
    #pragma unroll
    for (int i = 0; i < 4; ++i) {
      float lo = sr[i]   + __shfl_xor(sr[i],   4, 64);
      float hi = sr[i+4] + __shfl_xor(sr[i+4], 4, 64);
      v4[i] = (ln & 4) ? hi : lo;
    }
    float v2_[2];
    #pragma unroll
    for (int i = 0; i < 2; ++i) {
      float lo = v4[i]   + __shfl_xor(v4[i],   2, 64);
      float hi = v4[i+2] + __shfl_xor(v4[i+2], 2, 64);
      v2_[i] = (ln & 2) ? hi : lo;
    }
    float v1;
    {
      float lo = v2_[0] + __shfl_xor(v2_[0], 1, 64);
      float hi = v2_[1] + __shfl_xor(v2_[1], 1, 64);
      v1 = (ln & 1) ? hi : lo;
    }
    v1 += __shfl_xor(v1, 8, 64);
    v1 += __shfl_xor(v1, 16, 64);
    v1 += __shfl_xor(v1, 32, 64);
    // fast tanh: 1 - 2/(e^{2x}+1); exp2 saturates correctly at +-inf
    float zz  = v1 + dvc;
    float e2x = __builtin_amdgcn_exp2f(zz * 2.8853900817779268f);
    float val = 1.0f - 2.0f * __builtin_amdgcn_rcpf(e2x + 1.0f);
    float pv  = __shfl_xor(val, 1, 64);   // lane 2j gets row 2j+1's value
    const unsigned tg = ((unsigned)(t + 2) >> 1) & 1u;
    if (ln < 8 && !(ln & 1)) {
      union { unsigned long long u; unsigned ui[2]; } pk;
      pk.ui[0] = (__float_as_uint(val) & ~1u) | tg;
      pk.ui[1] = (__float_as_uint(pv)  & ~1u) | tg;
      __hip_atomic_store(
          sfb + (size_t)(t & 1)*slotstride + (blk*32 + w*4 + (ln >> 1)),
          pk.u, __ATOMIC_RELAXED, __HIP_MEMORY_SCOPE_AGENT);
      // plain store for the output GEMM (kernel-boundary visibility)
      *(float2*)(s + ((size_t)t*4 + b)*DIM + r0 + ln) = make_float2(val, pv);
    }
    // prefetch next step's g/d (independent of the ring)
    if (t + 1 < SEQ) {
      gvc = *(const float2*)(g + ((size_t)(t + 1)*4 + b)*DIM + 2*tid);
      dvc = dpre[((size_t)(t + 1)*4 + b)*DIM + myrow];
    }
    // no end barrier (r7): xs double-buffered; ring-reuse proof needs only
    // the stage barrier; next step's stage barrier bounds wave drift
  }
}

// ------------------------------------------------------------------------------
extern "C" void kernel_launch(void* const* d_in, const int* in_sizes, int n_in,
                              void* d_out, int out_size, void* d_ws, size_t ws_size,
                              hipStream_t stream)
{
  (void)in_sizes; (void)n_in; (void)out_size;
  const float* q   = (const float*)d_in[0];
  const float* k   = (const float*)d_in[1];
  const float* v   = (const float*)d_in[2];
  const float* Wi  = (const float*)d_in[3];
  const float* bi  = (const float*)d_in[4];
  const float* Wg  = (const float*)d_in[5];
  const float* bg  = (const float*)d_in[6];
  const float* A   = (const float*)d_in[7];
  const float* Bm  = (const float*)d_in[8];
  const float* Wo  = (const float*)d_in[9];
  const float* bo  = (const float*)d_in[10];
  const float* dec = (const float*)d_in[11];

  const size_t sf_bytes = (size_t)2*BATCH*512*sizeof(unsigned long long); // 32KB
  size_t need = (4*BIGN + 2*(size_t)64*4096)*sizeof(float) + sf_bytes;
  if (ws_size < need) return;

  float* b0 = (float*)d_ws;          // ret -> u -> s
  float* b1 = b0 + BIGN;             // inp
  float* b2 = b1 + BIGN;             // g
  float* b3 = b2 + BIGN;             // d  (pre-activation constant)
  float* E     = b3 + BIGN;
  float* carry = E + (size_t)64*4096;
  unsigned long long* sf = (unsigned long long*)(carry + (size_t)64*4096);
  float* outp  = (float*)d_out;

  hipMemsetAsync(sf, 0, sf_bytes, stream);

  scan_a<<<1024, 256, 0, stream>>>(k, v, dec, E);
  scan_b<<<16,   256, 0, stream>>>(E, dec, carry);
  scan_c<<<1024, 256, 0, stream>>>(q, k, v, dec, carry, b0);

  dim3 gg(DIM/GN, MROWS/GM);   // (8, 64)
  gemm_k<0><<<gg, 256, 0, stream>>>(b0, Wi, bi, b1, nullptr, nullptr, nullptr); // inp
  gemm_k<1><<<gg, 256, 0, stream>>>(b1, Wg, bg, b2, b1, b0, nullptr);           // g, u
  gemm_k<4><<<gg, 256, 0, stream>>>(b0, A,  nullptr, b3, nullptr, nullptr, nullptr); // d  = u@A^T
  gemm_k<2><<<gg, 256, 0, stream>>>(b1, Bm, nullptr, b3, nullptr, nullptr, nullptr); // d += inp@Bm^T

  recur_k<<<RBLK, 512, 0, stream>>>(A, b2, b3, b0, sf);                         // s

  gemm_k<3><<<gg, 256, 0, stream>>>(b0, Wo, bo, nullptr, nullptr, nullptr, outp); // out
}